// Round 7
// baseline (1132.225 us; speedup 1.0000x reference)
//
#include <hip/hip_runtime.h>

#define IMG_W 1024
#define SLICE 1048576   // 1024*1024, one (n,c) plane
#define INF_F __builtin_huge_valf()

// ---- DPP wave64 sum: canonical GCN row_shr/row_bcast chain, total lands in lane 63.
template <int CTRL>
__device__ __forceinline__ float dpp_add_step(float x) {
    int m = __builtin_amdgcn_update_dpp(0, __builtin_bit_cast(int, x), CTRL, 0xf, 0xf, true);
    return x + __builtin_bit_cast(float, m);
}
__device__ __forceinline__ float wave_sum63(float x) {
    x = dpp_add_step<0x111>(x);  // row_shr:1
    x = dpp_add_step<0x112>(x);  // row_shr:2
    x = dpp_add_step<0x114>(x);  // row_shr:4
    x = dpp_add_step<0x118>(x);  // row_shr:8
    x = dpp_add_step<0x142>(x);  // row_bcast:15
    x = dpp_add_step<0x143>(x);  // row_bcast:31
    return x;                    // lane 63 holds the wave total
}

typedef const float __attribute__((address_space(1))) gfloat;
typedef float __attribute__((address_space(3))) sfloat;

// ============================================================================
// L0: plane-fold with DOUBLE-BUFFERED plane pipeline (T3 minimum-2-phase).
// Diagnosis r2/r5/r6: single-buffered plane-fold = full vmcnt drain + 2
// barriers PER PLANE (24 drains/WG, 600-900cy each) -> VALUBusy pinned at 58%.
// Here: stage(p+1)->buf^1 + prefetch rf(p+1)->rfB are issued BEFORE
// compute(p), so every load has a whole compute phase to land; the
// __syncthreads() drain then costs ~0.  One barrier per plane.
//  - tile[2][16K] = 128 KB -> 1 WG/CU (8 waves, 2/SIMD).  SAD has >=4
//    independent dep chains/lane -> 2 waves/SIMD can saturate VALU issue.
//  - rfA/rfB named (rule #20); buffer selector is a literal at each call.
//  - VGPR est ~210; __launch_bounds__(512,1) caps at 256 under either
//    2nd-arg semantics (r6 lesson: (512,4) hard-capped at 64 -> 1.4 GB spill).
//    WRITE_SIZE is the spill tripwire.
// Grid (tx=32, byo=4, z=10): z = dxq*2+dyh; wave w owns by = byo*8+w;
// slice jj = ty-ty0 = w+yi in [0,16).  nd=4 di per WG.
// cost[(bx*32+by)*289 + di*17 + (dy+8)] = 12-plane summed MAD (valid only).
// ============================================================================
__global__ __launch_bounds__(512, 1) void hbma_l0(const float* __restrict__ ref,
                                                  const float* __restrict__ tgt,
                                                  float* __restrict__ cost) {
    const int tx  = blockIdx.x;        // target block row 0..31
    const int byo = blockIdx.y;        // by octet 0..3
    const int dxq = blockIdx.z >> 1;   // di quad 0..4
    const int dyh = blockIdx.z & 1;    // dy half
    const int di0 = dxq * 4;
    const int ndi = (dxq == 4) ? 1 : 4;
    const int t = threadIdx.x, lane = t & 63, w = t >> 6;
    const int by0 = byo * 8;
    const int by  = by0 + w;
    const int prow = lane >> 3, pcol = (lane & 7) << 2;
    const int dy0 = dyh ? 0 : -8;
    const int nyi = dyh ? 9 : 8;
    const int ty0 = by0 + dy0;         // slice jj = ty - ty0 = w + yi in [0,16)

    bool rvalid[4]; int bxv[4];
    bool any = false;
    #pragma unroll
    for (int d = 0; d < 4; ++d) {
        const int bx = tx - (di0 + d - 8);
        bxv[d] = bx;
        rvalid[d] = (d < ndi) && ((unsigned)bx < 32u);   // WG-uniform
        any = any || rvalid[d];
    }
    if (!any) return;   // WG-uniform early-out (before any barrier)

    __shared__ float tile[2][16 * 1024];   // 2 x 64 KB -> 1 WG/CU

    float acc[4][9];
    #pragma unroll
    for (int d = 0; d < 4; ++d)
        #pragma unroll
        for (int y = 0; y < 9; ++y) acc[d][y] = 0.f;

    // async stage of one plane's 16 slices into tile[sel].
    // LDS dest linear idx*16 B = wave-uniform base + lane*16 (64-aligned idx
    // ranges never cross a 256 slice boundary -> j wave-uniform).
    auto stage = [&](int plane, int sel) {
        const float* tgt_p = tgt + (size_t)plane * SLICE;
        #pragma unroll
        for (int s = 0; s < 8; ++s) {
            const int idx = t + 512 * s;
            const int j  = idx >> 8;
            const int ty = ty0 + j;
            if ((unsigned)ty < 32u) {   // wave-uniform
                const int ww = idx & 255;
                const int rr = ww >> 3;
                const int cc = (ww & 7) << 2;
                __builtin_amdgcn_global_load_lds(
                    (gfloat*)(tgt_p + (size_t)(tx * 32 + rr) * IMG_W + ty * 32 + cc),
                    (sfloat*)&tile[sel][idx * 4], 16, 0, 0);
            }
        }
    };

    // ref blocks for one plane into a named register block
    auto loadRf = [&](int plane, float4 (&rf)[4][4]) {
        const float* ref_p = ref + (size_t)plane * SLICE;
        #pragma unroll
        for (int d = 0; d < 4; ++d)
            if (rvalid[d]) {   // WG-uniform
                const float* rb = ref_p + (size_t)(bxv[d] * 32 + prow) * IMG_W + by * 32 + pcol;
                #pragma unroll
                for (int i = 0; i < 4; ++i)
                    rf[d][i] = *(const float4*)(rb + (size_t)i * 8 * IMG_W);
            }
    };

    auto computePlane = [&](int sel, const float4 (&rf)[4][4]) {
        #pragma unroll
        for (int yi = 0; yi < 9; ++yi) {
            if (yi < nyi) {                        // WG-uniform
                const int ty = by + dy0 + yi;
                if ((unsigned)ty < 32u) {          // wave-uniform
                    const int tb = (w + yi) * 1024 + prow * 32 + pcol;
                    float4 tv[4];
                    #pragma unroll
                    for (int i = 0; i < 4; ++i) tv[i] = *(const float4*)&tile[sel][tb + i * 256];
                    #pragma unroll
                    for (int d = 0; d < 4; ++d)
                        if (rvalid[d]) {           // WG-uniform
                            float4 a = {0.f, 0.f, 0.f, 0.f};
                            #pragma unroll
                            for (int i = 0; i < 4; ++i) {
                                a.x += __builtin_fabsf(rf[d][i].x - tv[i].x);
                                a.y += __builtin_fabsf(rf[d][i].y - tv[i].y);
                                a.z += __builtin_fabsf(rf[d][i].z - tv[i].z);
                                a.w += __builtin_fabsf(rf[d][i].w - tv[i].w);
                            }
                            acc[d][yi] += (a.x + a.y) + (a.z + a.w);
                        }
                }
            }
        }
    };

    float4 rfA[4][4], rfB[4][4];
    stage(0, 0);
    loadRf(0, rfA);
    __syncthreads();   // prologue drain (only drain that pays full latency)

    #pragma unroll 1   // keep one 2-plane body in icache
    for (int pp = 0; pp < 12; pp += 2) {
        // even plane: compute pp from buf0/rfA while pp+1 streams into buf1/rfB
        stage(pp + 1, 1);
        loadRf(pp + 1, rfB);
        computePlane(0, rfA);
        __syncthreads();   // pp+1 loads had the whole compute phase to land

        // odd plane: compute pp+1 from buf1/rfB while pp+2 streams into buf0/rfA
        if (pp + 2 < 12) {
            stage(pp + 2, 0);
            loadRf(pp + 2, rfA);
        }
        computePlane(1, rfB);
        __syncthreads();
    }

    // epilogue: one wave-reduce per candidate (amortized over 12 planes)
    #pragma unroll
    for (int d = 0; d < 4; ++d)
        if (rvalid[d]) {
            #pragma unroll
            for (int yi = 0; yi < 9; ++yi)
                if (yi < nyi) {
                    const int ty = by + dy0 + yi;
                    if ((unsigned)ty < 32u) {
                        const float s = wave_sum63(acc[d][yi]);
                        if (lane == 63)
                            cost[((size_t)bxv[d] * 32 + by) * 289 +
                                 (size_t)(di0 + d) * 17 + (dy0 + yi + 8)] = s;
                    }
                }
        }
}

// ============================================================================
// L1: fused parent-argmin prologue + child search.  One WG per PARENT; 4
// children share the 81-candidate window.  2-deep software pipeline (proven
// round-2 version).  XCD-chunked parent swizzle.  UNCHANGED this round.
// ============================================================================
__global__ __launch_bounds__(256) void hbma_l1(const float* __restrict__ ref,
                                               const float* __restrict__ tgt,
                                               const float* __restrict__ cost,
                                               float* __restrict__ out) {
    // XCD-chunked swizzle: pid -> (pbx, pby), 8 chunks of 4 pbx-rows each.
    const int pid = blockIdx.y * 32 + blockIdx.x;
    const int pbx = ((pid & 7) << 2) + ((pid >> 3) >> 5);
    const int pby = (pid >> 3) & 31;
    const int t = threadIdx.x;
    const int lane = t & 63, w = t >> 6;

    __shared__ float partials[4][81][4];
    __shared__ int2 sbest[4];
    __shared__ float pm_c[4];
    __shared__ int pm_k[4];

    // ---- parent argmin over 289 candidates (first-min in lex (dx,dy) order)
    float bc = INF_F; int bk = 1 << 30;
    {
        const float* crow = cost + ((size_t)pbx * 32 + pby) * 289;
        for (int k = t; k < 289; k += 256) {
            const int dx = k / 17 - 8, dy = k % 17 - 8;
            if ((unsigned)(pbx + dx) < 32u && (unsigned)(pby + dy) < 32u) {
                const float c = crow[k];
                if (c < bc) { bc = c; bk = k; }
            }
        }
        #pragma unroll
        for (int o = 32; o > 0; o >>= 1) {
            const float oc = __shfl_down(bc, o, 64);
            const int   ok = __shfl_down(bk, o, 64);
            if (oc < bc || (oc == bc && ok < bk)) { bc = oc; bk = ok; }
        }
        if (lane == 0) { pm_c[w] = bc; pm_k[w] = bk; }
        __syncthreads();
        bc = pm_c[0]; bk = pm_k[0];
        #pragma unroll
        for (int j = 1; j < 4; ++j) {
            const float oc = pm_c[j]; const int ok = pm_k[j];
            if (oc < bc || (oc == bc && ok < bk)) { bc = oc; bk = ok; }
        }
    }
    const int cx = 2 * (pbx + bk / 17 - 8);
    const int cy = 2 * (pby + bk % 17 - 8);

    // thread's 12-px footprint of a 16x16x12 child block (3 float4s)
    int off[3];
    #pragma unroll
    for (int i = 0; i < 3; ++i) {
        const int e4 = t + 256 * i;
        const int nc = e4 >> 6;
        const int ww = e4 & 63;
        off[i] = nc * SLICE + (ww >> 2) * IMG_W + ((ww & 3) << 2);
    }
    int cbase[4];
    float4 rf[4][3];
    #pragma unroll
    for (int c = 0; c < 4; ++c) {
        const int bx = 2 * pbx + (c >> 1), by = 2 * pby + (c & 1);
        cbase[c] = (bx * 16) * IMG_W + by * 16;
        #pragma unroll
        for (int i = 0; i < 3; ++i)
            rf[c][i] = *(const float4*)(ref + cbase[c] + off[i]);
    }

    auto issue = [&](int k, float4 (&tv)[3]) -> bool {
        const int ttx = cx + k / 9 - 4;
        const int tty = cy + k % 9 - 4;
        const bool valid = ((unsigned)ttx < 64u) && ((unsigned)tty < 64u);
        if (valid) {   // WG-uniform
            const float* tb = tgt + (ttx * 16) * IMG_W + tty * 16;
            #pragma unroll
            for (int i = 0; i < 3; ++i) tv[i] = *(const float4*)(tb + off[i]);
        }
        return valid;
    };
    auto compute = [&](int k, const float4 (&tv)[3], bool valid) {
        if (k >= 81) return;           // WG-uniform
        if (valid) {                   // WG-uniform
            #pragma unroll
            for (int c = 0; c < 4; ++c) {
                float4 a = {0.f, 0.f, 0.f, 0.f};
                #pragma unroll
                for (int i = 0; i < 3; ++i) {
                    a.x += __builtin_fabsf(rf[c][i].x - tv[i].x);
                    a.y += __builtin_fabsf(rf[c][i].y - tv[i].y);
                    a.z += __builtin_fabsf(rf[c][i].z - tv[i].z);
                    a.w += __builtin_fabsf(rf[c][i].w - tv[i].w);
                }
                const float s = wave_sum63((a.x + a.y) + (a.z + a.w));
                if (lane == 63) partials[c][k][w] = s;
            }
        } else if (lane == 63) {
            #pragma unroll
            for (int c = 0; c < 4; ++c) partials[c][k][w] = INF_F;
        }
    };

    // 2-deep pipelined candidate loop (named slots only: rule #20)
    float4 tvA[3], tvB[3];
    bool vA = issue(0, tvA);
    for (int k = 0; k < 81; k += 2) {
        const bool vB = (k + 1 < 81) && issue(k + 1, tvB);
        compute(k, tvA, vA);
        const bool vA2 = (k + 2 < 81) && issue(k + 2, tvA);
        compute(k + 1, tvB, vB);
        vA = vA2;
    }
    __syncthreads();

    // wave w finds argmin for child w
    {
        const int c = w;
        float cbc = INF_F; int cbk = 1 << 30;
        for (int k = lane; k < 81; k += 64) {
            const float4 p4 = *(const float4*)&partials[c][k][0];
            const float cst = (p4.x + p4.y) + (p4.z + p4.w);
            if (cst < cbc) { cbc = cst; cbk = k; }
        }
        #pragma unroll
        for (int o = 32; o > 0; o >>= 1) {
            const float oc = __shfl_down(cbc, o, 64);
            const int   ok = __shfl_down(cbk, o, 64);
            if (oc < cbc || (oc == cbc && ok < cbk)) { cbc = oc; cbk = ok; }
        }
        if (lane == 0) sbest[c] = make_int2(cx + cbk / 9 - 4, cy + cbk % 9 - 4);
    }
    __syncthreads();

    // motion vectors: out[0..32767] as [N=4][2][64][64] (same for all n)
    if (t < 32) {
        const int c = t >> 3, n = (t >> 1) & 3, ch = t & 1;
        const int bx = 2 * pbx + (c >> 1), by = 2 * pby + (c & 1);
        const int2 fb = sbest[c];
        out[((n * 2 + ch) * 64 + bx) * 64 + by] = (ch == 0) ? (float)(fb.x - bx) : (float)(fb.y - by);
    }

    // predicted frame gather for all 4 children
    float* pred = out + 32768;
    #pragma unroll
    for (int c = 0; c < 4; ++c) {
        const int2 fb = sbest[c];
        const float* sb = tgt + (fb.x * 16) * IMG_W + fb.y * 16;
        float* db = pred + cbase[c];
        #pragma unroll
        for (int i = 0; i < 3; ++i)
            *(float4*)(db + off[i]) = *(const float4*)(sb + off[i]);
    }
}

extern "C" void kernel_launch(void* const* d_in, const int* in_sizes, int n_in,
                              void* d_out, int out_size, void* d_ws, size_t ws_size,
                              hipStream_t stream) {
    const float* ref = (const float*)d_in[0];
    const float* tgt = (const float*)d_in[1];
    float* out = (float*)d_out;

    float* cost = (float*)d_ws;   // 1024 blocks * 289 candidates * 4 B = 1.18 MB

    hbma_l0<<<dim3(32, 4, 10), 512, 0, stream>>>(ref, tgt, cost);
    hbma_l1<<<dim3(32, 32), 256, 0, stream>>>(ref, tgt, cost, out);
}

// Round 8
// 488.395 us; speedup vs baseline: 2.3183x; 2.3183x over previous
//
#include <hip/hip_runtime.h>

#define IMG_W 1024
#define SLICE 1048576   // 1024*1024, one (n,c) plane
#define INF_F __builtin_huge_valf()
#define WS_PART_FLOATS (12 * 1024 * 289)   // phase-1 partials [plane][bx*32+by][k]

// ---- DPP wave64 sum: canonical GCN row_shr/row_bcast chain, total lands in lane 63.
template <int CTRL>
__device__ __forceinline__ float dpp_add_step(float x) {
    int m = __builtin_amdgcn_update_dpp(0, __builtin_bit_cast(int, x), CTRL, 0xf, 0xf, true);
    return x + __builtin_bit_cast(float, m);
}
__device__ __forceinline__ float wave_sum63(float x) {
    x = dpp_add_step<0x111>(x);  // row_shr:1
    x = dpp_add_step<0x112>(x);  // row_shr:2
    x = dpp_add_step<0x114>(x);  // row_shr:4
    x = dpp_add_step<0x118>(x);  // row_shr:8
    x = dpp_add_step<0x142>(x);  // row_bcast:15
    x = dpp_add_step<0x143>(x);  // row_bcast:31
    return x;                    // lane 63 holds the wave total
}

// ============================================================================
// L0 phase 1 (PROVEN round-0 kernel, 261 us, VALU 75%, VGPR 60): per-plane
// partial MAD costs with 4-ref register reuse.  Plane-fold variants (r1-r7)
// all lost to this shape: their acc/rf register demand (>128 VGPR) either
// spilled (WRITE_SIZE ballooned to 0.4-1.4 GB) or halved occupancy; the
// allocator never grants >128 VGPR regardless of __launch_bounds__.
// Grid (tx=32, byq=4, plane=12), 512 threads = 8 waves; wave w owns by=byq*8+w.
// Target row tx staged in LDS per dy-batch; refs (4 dx values) in registers.
// part[plane][bx*32+by][ (dx+8)*17 + (dy+8) ] = per-plane cost sum (valid only).
// ============================================================================
__global__ __launch_bounds__(512, 4) void hbma_l0_phase1(const float* __restrict__ ref,
                                                         const float* __restrict__ tgt,
                                                         float* __restrict__ part) {
    const int tx    = blockIdx.x;   // target block row 0..31
    const int byq   = blockIdx.y;   // by quarter 0..3
    const int plane = blockIdx.z;   // 0..11
    const int t = threadIdx.x;
    const int lane = t & 63, w = t >> 6;
    const int by0 = byq * 8;
    const int by  = by0 + w;

    __shared__ float tile[16 * 1024];   // 16 block-plane slices of the target row (64 KB)

    // lane's pixel footprint inside a 32x32 block-plane: rows prow+8i, cols pcol..pcol+3
    const int prow = lane >> 3;
    const int pcol = (lane & 7) << 2;

    const float* tgt_p = tgt + (size_t)plane * SLICE;
    const float* ref_p = ref + (size_t)plane * SLICE;

    for (int batch = 0; batch < 2; ++batch) {
        const int tyBase = (batch == 0) ? (by0 - 8) : by0;
        const int dyLo   = (batch == 0) ? -8 : 0;
        const int dyHi   = (batch == 0) ? -1 : 8;

        __syncthreads();   // previous batch fully consumed
        // cooperative stage: up to 16 valid slices, float4 per thread per step
        for (int idx = t; idx < 16 * 256; idx += 512) {
            const int j  = idx >> 8;
            const int ty = tyBase + j;
            if ((unsigned)ty < 32u) {
                const int ww = idx & 255;
                const int rr = ww >> 3;
                const int cc = (ww & 7) << 2;
                *(float4*)&tile[j * 1024 + rr * 32 + cc] =
                    *(const float4*)(tgt_p + (size_t)(tx * 32 + rr) * IMG_W + ty * 32 + cc);
            }
        }
        __syncthreads();

        for (int dxg = 0; dxg < 5; ++dxg) {
            // load up to 4 ref blocks (di = dxg*4+r, dx = di-8, bx = tx-dx)
            float4 rf[4][4];
            bool rvalid[4];
            #pragma unroll
            for (int r = 0; r < 4; ++r) {
                const int di = dxg * 4 + r;
                const int bx = tx - (di - 8);
                rvalid[r] = (di <= 16) && ((unsigned)bx < 32u);
                if (rvalid[r]) {
                    const float* rb = ref_p + (size_t)(bx * 32 + prow) * IMG_W + by * 32 + pcol;
                    #pragma unroll
                    for (int i = 0; i < 4; ++i)
                        rf[r][i] = *(const float4*)(rb + (size_t)i * 8 * IMG_W);
                }
            }
            for (int dy = dyLo; dy <= dyHi; ++dy) {
                const int ty = by + dy;
                if ((unsigned)ty >= 32u) continue;      // wave-uniform
                const int tbase = (ty - tyBase) * 1024 + prow * 32 + pcol;
                float4 tv[4];
                #pragma unroll
                for (int i = 0; i < 4; ++i)
                    tv[i] = *(const float4*)&tile[tbase + i * 256];
                #pragma unroll
                for (int r = 0; r < 4; ++r) {
                    if (!rvalid[r]) continue;           // wave-uniform
                    float4 a = {0.f, 0.f, 0.f, 0.f};
                    #pragma unroll
                    for (int i = 0; i < 4; ++i) {
                        a.x += __builtin_fabsf(rf[r][i].x - tv[i].x);
                        a.y += __builtin_fabsf(rf[r][i].y - tv[i].y);
                        a.z += __builtin_fabsf(rf[r][i].z - tv[i].z);
                        a.w += __builtin_fabsf(rf[r][i].w - tv[i].w);
                    }
                    const float s = wave_sum63((a.x + a.y) + (a.z + a.w));
                    if (lane == 63) {
                        const int di = dxg * 4 + r;
                        const int bx = tx - (di - 8);
                        part[((size_t)plane * 1024 + bx * 32 + by) * 289 + di * 17 + (dy + 8)] = s;
                    }
                }
            }
        }
    }
}

// ============================================================================
// L1: fused parent-argmin prologue (sums the 12 per-plane partials in-WG,
// replacing the old phase-2 kernel + its launch) + child search.  One WG per
// PARENT; 4 children share the 81-candidate window.  2-deep software pipeline
// (proven round-2 version).  XCD-chunked parent swizzle.
// ============================================================================
__global__ __launch_bounds__(256) void hbma_l1(const float* __restrict__ ref,
                                               const float* __restrict__ tgt,
                                               const float* __restrict__ part,
                                               float* __restrict__ out) {
    // XCD-chunked swizzle: pid -> (pbx, pby), 8 chunks of 4 pbx-rows each.
    const int pid = blockIdx.y * 32 + blockIdx.x;
    const int pbx = ((pid & 7) << 2) + ((pid >> 3) >> 5);
    const int pby = (pid >> 3) & 31;
    const int t = threadIdx.x;
    const int lane = t & 63, w = t >> 6;

    __shared__ float partials[4][81][4];
    __shared__ int2 sbest[4];
    __shared__ float pm_c[4];
    __shared__ int pm_k[4];

    // ---- parent argmin over 289 candidates, summing 12 planes (first-min
    // in lex (dx,dy) order; matches reference scan order)
    float bc = INF_F; int bk = 1 << 30;
    {
        const size_t blk = (size_t)pbx * 32 + pby;
        for (int k = t; k < 289; k += 256) {
            const int dx = k / 17 - 8, dy = k % 17 - 8;
            if ((unsigned)(pbx + dx) < 32u && (unsigned)(pby + dy) < 32u) {
                float c = 0.f;
                #pragma unroll
                for (int p = 0; p < 12; ++p)
                    c += part[((size_t)p * 1024 + blk) * 289 + k];
                if (c < bc) { bc = c; bk = k; }
            }
        }
        #pragma unroll
        for (int o = 32; o > 0; o >>= 1) {
            const float oc = __shfl_down(bc, o, 64);
            const int   ok = __shfl_down(bk, o, 64);
            if (oc < bc || (oc == bc && ok < bk)) { bc = oc; bk = ok; }
        }
        if (lane == 0) { pm_c[w] = bc; pm_k[w] = bk; }
        __syncthreads();
        bc = pm_c[0]; bk = pm_k[0];
        #pragma unroll
        for (int j = 1; j < 4; ++j) {
            const float oc = pm_c[j]; const int ok = pm_k[j];
            if (oc < bc || (oc == bc && ok < bk)) { bc = oc; bk = ok; }
        }
    }
    const int cx = 2 * (pbx + bk / 17 - 8);
    const int cy = 2 * (pby + bk % 17 - 8);

    // thread's 12-px footprint of a 16x16x12 child block (3 float4s)
    int off[3];
    #pragma unroll
    for (int i = 0; i < 3; ++i) {
        const int e4 = t + 256 * i;
        const int nc = e4 >> 6;
        const int ww = e4 & 63;
        off[i] = nc * SLICE + (ww >> 2) * IMG_W + ((ww & 3) << 2);
    }
    int cbase[4];
    float4 rf[4][3];
    #pragma unroll
    for (int c = 0; c < 4; ++c) {
        const int bx = 2 * pbx + (c >> 1), by = 2 * pby + (c & 1);
        cbase[c] = (bx * 16) * IMG_W + by * 16;
        #pragma unroll
        for (int i = 0; i < 3; ++i)
            rf[c][i] = *(const float4*)(ref + cbase[c] + off[i]);
    }

    auto issue = [&](int k, float4 (&tv)[3]) -> bool {
        const int ttx = cx + k / 9 - 4;
        const int tty = cy + k % 9 - 4;
        const bool valid = ((unsigned)ttx < 64u) && ((unsigned)tty < 64u);
        if (valid) {   // WG-uniform
            const float* tb = tgt + (ttx * 16) * IMG_W + tty * 16;
            #pragma unroll
            for (int i = 0; i < 3; ++i) tv[i] = *(const float4*)(tb + off[i]);
        }
        return valid;
    };
    auto compute = [&](int k, const float4 (&tv)[3], bool valid) {
        if (k >= 81) return;           // WG-uniform
        if (valid) {                   // WG-uniform
            #pragma unroll
            for (int c = 0; c < 4; ++c) {
                float4 a = {0.f, 0.f, 0.f, 0.f};
                #pragma unroll
                for (int i = 0; i < 3; ++i) {
                    a.x += __builtin_fabsf(rf[c][i].x - tv[i].x);
                    a.y += __builtin_fabsf(rf[c][i].y - tv[i].y);
                    a.z += __builtin_fabsf(rf[c][i].z - tv[i].z);
                    a.w += __builtin_fabsf(rf[c][i].w - tv[i].w);
                }
                const float s = wave_sum63((a.x + a.y) + (a.z + a.w));
                if (lane == 63) partials[c][k][w] = s;
            }
        } else if (lane == 63) {
            #pragma unroll
            for (int c = 0; c < 4; ++c) partials[c][k][w] = INF_F;
        }
    };

    // 2-deep pipelined candidate loop (named slots only: rule #20)
    float4 tvA[3], tvB[3];
    bool vA = issue(0, tvA);
    for (int k = 0; k < 81; k += 2) {
        const bool vB = (k + 1 < 81) && issue(k + 1, tvB);
        compute(k, tvA, vA);
        const bool vA2 = (k + 2 < 81) && issue(k + 2, tvA);
        compute(k + 1, tvB, vB);
        vA = vA2;
    }
    __syncthreads();

    // wave w finds argmin for child w
    {
        const int c = w;
        float cbc = INF_F; int cbk = 1 << 30;
        for (int k = lane; k < 81; k += 64) {
            const float4 p4 = *(const float4*)&partials[c][k][0];
            const float cst = (p4.x + p4.y) + (p4.z + p4.w);
            if (cst < cbc) { cbc = cst; cbk = k; }
        }
        #pragma unroll
        for (int o = 32; o > 0; o >>= 1) {
            const float oc = __shfl_down(cbc, o, 64);
            const int   ok = __shfl_down(cbk, o, 64);
            if (oc < cbc || (oc == cbc && ok < cbk)) { cbc = oc; cbk = ok; }
        }
        if (lane == 0) sbest[c] = make_int2(cx + cbk / 9 - 4, cy + cbk % 9 - 4);
    }
    __syncthreads();

    // motion vectors: out[0..32767] as [N=4][2][64][64] (same for all n)
    if (t < 32) {
        const int c = t >> 3, n = (t >> 1) & 3, ch = t & 1;
        const int bx = 2 * pbx + (c >> 1), by = 2 * pby + (c & 1);
        const int2 fb = sbest[c];
        out[((n * 2 + ch) * 64 + bx) * 64 + by] = (ch == 0) ? (float)(fb.x - bx) : (float)(fb.y - by);
    }

    // predicted frame gather for all 4 children
    float* pred = out + 32768;
    #pragma unroll
    for (int c = 0; c < 4; ++c) {
        const int2 fb = sbest[c];
        const float* sb = tgt + (fb.x * 16) * IMG_W + fb.y * 16;
        float* db = pred + cbase[c];
        #pragma unroll
        for (int i = 0; i < 3; ++i)
            *(float4*)(db + off[i]) = *(const float4*)(sb + off[i]);
    }
}

extern "C" void kernel_launch(void* const* d_in, const int* in_sizes, int n_in,
                              void* d_out, int out_size, void* d_ws, size_t ws_size,
                              hipStream_t stream) {
    const float* ref = (const float*)d_in[0];
    const float* tgt = (const float*)d_in[1];
    float* out = (float*)d_out;

    float* part = (float*)d_ws;   // 14.2 MB per-plane partials

    hbma_l0_phase1<<<dim3(32, 4, 12), 512, 0, stream>>>(ref, tgt, part);
    hbma_l1<<<dim3(32, 32), 256, 0, stream>>>(ref, tgt, part, out);
}